// Round 12
// baseline (209.522 us; speedup 1.0000x reference)
//
#include <hip/hip_runtime.h>
#include <stdint.h>

// Problem constants (match reference)
#define BATCH    256
#define MPTS     512
#define KNN      33
#define RADIUS_F 5.0f
#define EDGES    (BATCH * MPTS * KNN)   // 4,325,376 edges; out = 4*EDGES float32

#define BLOCKS_PER_GRAPH 8
#define ROWS_PER_BLOCK   64             // MPTS / BLOCKS_PER_GRAPH
#define THREADS          256
#define WAVES_PER_BLOCK  4              // THREADS / 64
// Each wave processes TWO rows concurrently; per-lane sorted candidate lists
// live in LDS (10 slots: 8 keys + 2 sentinels) with a per-lane cursor.
// Each round extracts the top-2 (16 rounds instead of 32 -> half the serial
// cross-lane chains, which R8-R11 showed are the binder).

// compare-exchange on u32 keys: 1 cmp + 2 cndmask
static __device__ __forceinline__ void ce(uint32_t& a, uint32_t& b) {
    const uint32_t lo = a < b ? a : b;
    const uint32_t hi = a < b ? b : a;
    a = lo; b = hi;
}

// DPP min step with IDENTITY old — fuses to a single v_min_u32_dpp
// (validated R10: 240 -> 188 us).
template <int CTRL, int ROWM>
static __device__ __forceinline__ uint32_t dpp_min(uint32_t x) {
    const uint32_t t = (uint32_t)__builtin_amdgcn_update_dpp(
        (int)0xFFFFFFFFu, (int)x, CTRL, ROWM, 0xF, false);
    return t < x ? t : x;
}

// Reduce 64 lane values to min in lane 63 (6 fused DPP steps).
static __device__ __forceinline__ uint32_t reduce63(uint32_t x) {
    x = dpp_min<0x111, 0xF>(x);  // row_shr:1
    x = dpp_min<0x112, 0xF>(x);  // row_shr:2
    x = dpp_min<0x114, 0xF>(x);  // row_shr:4
    x = dpp_min<0x118, 0xF>(x);  // row_shr:8
    x = dpp_min<0x142, 0xA>(x);  // row_bcast:15 -> rows 1,3
    x = dpp_min<0x143, 0xC>(x);  // row_bcast:31 -> rows 2,3
    return x;
}

#define SORT19(S)                                                        \
    do {                                                                 \
        ce(S[0], S[1]); ce(S[2], S[3]); ce(S[4], S[5]); ce(S[6], S[7]);  \
        ce(S[0], S[2]); ce(S[1], S[3]); ce(S[4], S[6]); ce(S[5], S[7]);  \
        ce(S[1], S[2]); ce(S[5], S[6]); ce(S[0], S[4]); ce(S[3], S[7]);  \
        ce(S[1], S[5]); ce(S[2], S[6]);                                  \
        ce(S[1], S[4]); ce(S[3], S[6]);                                  \
        ce(S[2], S[4]); ce(S[3], S[5]);                                  \
        ce(S[3], S[4]);                                                  \
    } while (0)

__global__ void __launch_bounds__(THREADS)
InteractionModule_50483045597845_kernel(const float* __restrict__ pos,
                                        float* __restrict__ out) {
    // 8 KB: one graph's 512 points as (x, y, z, |p|^2)
    __shared__ float4 spt[MPTS];
    // 20 KB: per-(wave,row) sorted lists, transposed: keys[r][c*64 + lane],
    // c = 0..9 (slots 8,9 = sentinels so head+1 reads never run off the end).
    // bank = lane % 32 -> conflict-free for any per-lane cursor mix.
    __shared__ uint32_t keys[WAVES_PER_BLOCK * 2][10 * 64];

    const int graph = blockIdx.x / BLOCKS_PER_GRAPH;
    const int slice = blockIdx.x - graph * BLOCKS_PER_GRAPH;
    const int tid   = (int)threadIdx.x;

    for (int p = tid; p < MPTS; p += THREADS) {
        const float* pp = pos + (size_t)(graph * MPTS + p) * 3;
        const float x = pp[0], y = pp[1], z = pp[2];
        // fma-chain |p|^2 — matches dot() below exactly so self-edge d2 == 0
        const float sq = __builtin_fmaf(x, x, __builtin_fmaf(y, y, __fmul_rn(z, z)));
        spt[p] = make_float4(x, y, z, sq);
    }
    __syncthreads();

    const int lane = tid & 63;
    const int wave = tid >> 6;

    uint32_t* const krA = &keys[wave][0];
    uint32_t* const krB = &keys[wave + WAVES_PER_BLOCK][0];

    // 8 outer iterations × (4 waves × 2 rows) = 64 rows per block.
    #pragma unroll 1
    for (int it = 0; it < ROWS_PER_BLOCK / (WAVES_PER_BLOCK * 2); ++it) {
        const int mA   = slice * ROWS_PER_BLOCK + it * (WAVES_PER_BLOCK * 2) + wave;
        const int mB   = mA + WAVES_PER_BLOCK;
        const int rowA = graph * MPTS + mA;
        const int rowB = graph * MPTS + mB;

        const float4 pa = spt[mA];
        const float4 pb = spt[mB];

        // Lane holds candidates n = lane + 64*j for BOTH rows (shared q load).
        // 32-bit key = (d2bits & ~7) | j; 8-ulp truncation perturbs only
        // near-exact ties (validated R6-R11: absmax 512, no mask flips).
        uint32_t sA[8], sB[8];
        #pragma unroll
        for (int j = 0; j < 8; ++j) {
            const int n = lane + (j << 6);
            const float4 q = spt[n];
            const float dotA = __builtin_fmaf(pa.x, q.x,
                               __builtin_fmaf(pa.y, q.y, __fmul_rn(pa.z, q.z)));
            const float dotB = __builtin_fmaf(pb.x, q.x,
                               __builtin_fmaf(pb.y, q.y, __fmul_rn(pb.z, q.z)));
            float d2A = __builtin_fmaf(-2.0f, dotA, __fadd_rn(pa.w, q.w));
            float d2B = __builtin_fmaf(-2.0f, dotB, __fadd_rn(pb.w, q.w));
            d2A = fmaxf(d2A, 0.0f);
            d2B = fmaxf(d2B, 0.0f);
            sA[j] = (__float_as_uint(d2A) & 0xFFFFFFF8u) | (uint32_t)j;
            sB[j] = (__float_as_uint(d2B) & 0xFFFFFFF8u) | (uint32_t)j;
        }

        // Sort each lane's 8 keys ascending (19-CE network, both rows).
        SORT19(sA);
        SORT19(sB);

        // Spill sorted lists + 2 sentinel slots to this wave's LDS regions.
        // Same-wave producer/consumer: lgkmcnt ordering only, no barrier.
        #pragma unroll
        for (int c = 0; c < 8; ++c) {
            krA[c * 64 + lane] = sA[c];
            krB[c * 64 + lane] = sB[c];
        }
        krA[8 * 64 + lane] = 0xFFFFFFFFu;
        krB[8 * 64 + lane] = 0xFFFFFFFFu;
        krA[9 * 64 + lane] = 0xFFFFFFFFu;
        krB[9 * 64 + lane] = 0xFFFFFFFFu;

        // Per-lane cursor (dword units, slot = cursor/64). k = 0 is the self
        // edge (key exactly j, global min): pre-consume by starting at slot 1.
        int cA = (lane == (mA & 63)) ? 64 : 0;
        int cB = (lane == (mB & 63)) ? 64 : 0;

        int keptA = mA;   // lane 0's slot: self neighbor
        int keptB = mB;
        // 16 rounds × 2 extractions = ranks 1..32.
        #pragma unroll 1
        for (int k = 1; k < KNN; k += 2) {
            // heads + next elements (compiler can fuse into ds_read2_b32)
            const uint32_t hA  = krA[cA + lane];
            const uint32_t h2A = krA[cA + lane + 64];
            const uint32_t hB  = krB[cB + lane];
            const uint32_t h2B = krB[cB + lane + 64];

            // -------- first minimum of the round --------
            const uint32_t m1A =
                (uint32_t)__builtin_amdgcn_readlane((int)reduce63(hA), 63);
            const uint32_t m1B =
                (uint32_t)__builtin_amdgcn_readlane((int)reduce63(hB), 63);
            const int w1A = __ffsll(__ballot(hA == m1A)) - 1;
            const int w1B = __ffsll(__ballot(hB == m1B)) - 1;

            // -------- second minimum: replace w1's head with its next --------
            // remaining multiset's min = min(heads != w1, w1's next element)
            const uint32_t hxA = (lane == w1A) ? h2A : hA;
            const uint32_t hxB = (lane == w1B) ? h2B : hB;
            const uint32_t m2A =
                (uint32_t)__builtin_amdgcn_readlane((int)reduce63(hxA), 63);
            const uint32_t m2B =
                (uint32_t)__builtin_amdgcn_readlane((int)reduce63(hxB), 63);
            const int w2A = __ffsll(__ballot(hxA == m2A)) - 1;  // may equal w1A
            const int w2B = __ffsll(__ballot(hxB == m2B)) - 1;

            // neighbor indices (SALU): n = winner_lane + (j from key bits)<<6
            const int n1A = w1A + (int)((m1A & 7u) << 6);
            const int n2A = w2A + (int)((m2A & 7u) << 6);
            const int n1B = w1B + (int)((m1B & 7u) << 6);
            const int n2B = w2B + (int)((m2B & 7u) << 6);

            // lanes k, k+1 record this round's two neighbors (shared cmps)
            const bool sel1 = (lane == k);
            const bool sel2 = (lane == k + 1);
            keptA = sel1 ? n1A : keptA;
            keptA = sel2 ? n2A : keptA;
            keptB = sel1 ? n1B : keptB;
            keptB = sel2 ? n2B : keptB;

            // winners advance cursors (w2 == w1 -> that lane advances by 2)
            cA += ((lane == w1A) ? 64 : 0) + ((lane == w2A) ? 64 : 0);
            cB += ((lane == w1B) ? 64 : 0) + ((lane == w2B) ? 64 : 0);
        }

        // Epilogue: lanes 0..32 emit edge k = lane for both rows.
        // dist/mask recomputed exactly as numpy fp32 (rn ops, same order) —
        // bit-identical given identical (src,dst).
        if (lane < KNN) {
            {
                const float4 q = spt[keptA];
                const float dx = __fsub_rn(q.x, pa.x);
                const float dy = __fsub_rn(q.y, pa.y);
                const float dz = __fsub_rn(q.z, pa.z);
                const float ss = __fadd_rn(__fadd_rn(__fmul_rn(dx, dx),
                                                     __fmul_rn(dy, dy)),
                                           __fmul_rn(dz, dz));
                const float dist  = (ss > 0.0f) ? __fsqrt_rn(ss) : 0.0f;
                const float maskv = (dist <= RADIUS_F) ? 1.0f : 0.0f;
                const size_t e    = (size_t)rowA * KNN + (size_t)lane;
                out[e]                     = (float)(graph * MPTS + keptA);
                out[(size_t)EDGES + e]     = (float)rowA;
                out[2 * (size_t)EDGES + e] = dist;
                out[3 * (size_t)EDGES + e] = maskv;
            }
            {
                const float4 q = spt[keptB];
                const float dx = __fsub_rn(q.x, pb.x);
                const float dy = __fsub_rn(q.y, pb.y);
                const float dz = __fsub_rn(q.z, pb.z);
                const float ss = __fadd_rn(__fadd_rn(__fmul_rn(dx, dx),
                                                     __fmul_rn(dy, dy)),
                                           __fmul_rn(dz, dz));
                const float dist  = (ss > 0.0f) ? __fsqrt_rn(ss) : 0.0f;
                const float maskv = (dist <= RADIUS_F) ? 1.0f : 0.0f;
                const size_t e    = (size_t)rowB * KNN + (size_t)lane;
                out[e]                     = (float)(graph * MPTS + keptB);
                out[(size_t)EDGES + e]     = (float)rowB;
                out[2 * (size_t)EDGES + e] = dist;
                out[3 * (size_t)EDGES + e] = maskv;
            }
        }
    }
}

extern "C" void kernel_launch(void* const* d_in, const int* in_sizes, int n_in,
                              void* d_out, int out_size, void* d_ws, size_t ws_size,
                              hipStream_t stream) {
    (void)in_sizes; (void)n_in; (void)out_size; (void)d_ws; (void)ws_size;
    const float* pos = (const float*)d_in[0];   // d_in[1] (batch) implied by layout
    float*       out = (float*)d_out;
    hipLaunchKernelGGL(InteractionModule_50483045597845_kernel,
                       dim3(BATCH * BLOCKS_PER_GRAPH), dim3(THREADS), 0, stream,
                       pos, out);
}